// Round 1
// baseline (357.271 us; speedup 1.0000x reference)
//
#include <hip/hip_runtime.h>
#include <math.h>

#define C_ 2000
#define B_ 4096
#define NCH 32
#define RPC (B_ / NCH)   // 128 rows per chunk
#define KK 3

// ---- workspace layout (bytes) ----
constexpr size_t OFF_ACC    = 0;                               // 3 doubles (bce, dp, dn)
constexpr size_t OFF_COUNTS = 256;                             // int[C]
constexpr size_t OFF_M      = OFF_COUNTS + 4*(size_t)C_;       // int[C]
constexpr size_t OFF_NN     = OFF_M      + 4*(size_t)C_;       // int[C]
constexpr size_t OFF_MIN    = OFF_NN     + 4*(size_t)C_;       // int[C]
constexpr size_t OFF_PTV    = OFF_MIN    + 4*(size_t)C_;       // float[4C] pos_top (cleaned)
constexpr size_t OFF_PTR    = OFF_PTV    + 16*(size_t)C_;      // int[4C]   pos_row
constexpr size_t OFF_NTV    = OFF_PTR    + 16*(size_t)C_;      // float[3C] neg_top (cleaned)
constexpr size_t OFF_PNP    = OFF_NTV    + 12*(size_t)C_;      // int[NCH*C] partial npos
constexpr size_t OFF_PPV    = OFF_PNP    + 4*(size_t)NCH*C_;   // float[NCH*C*4]
constexpr size_t OFF_PPR    = OFF_PPV    + 16*(size_t)NCH*C_;  // int[NCH*C*4]
constexpr size_t OFF_PNV    = OFF_PPR    + 16*(size_t)NCH*C_;  // float[NCH*C*3]
// total ~3.2 MB

// stable lexicographic (v, r) insert into ascending 4-list; sentinels (INF,-1)
// never collide with real entries (preds are finite). Explicit chain: no
// dynamic register-array indexing (avoids scratch spill).
__device__ __forceinline__ void ins4(float v, int r, float* pv, int* pr) {
    if (!((v < pv[3]) || (v == pv[3] && r < pr[3]))) return;
    if (!((v < pv[2]) || (v == pv[2] && r < pr[2]))) { pv[3]=v; pr[3]=r; return; }
    pv[3]=pv[2]; pr[3]=pr[2];
    if (!((v < pv[1]) || (v == pv[1] && r < pr[1]))) { pv[2]=v; pr[2]=r; return; }
    pv[2]=pv[1]; pr[2]=pr[1];
    if (!((v < pv[0]) || (v == pv[0] && r < pr[0]))) { pv[1]=v; pr[1]=r; return; }
    pv[1]=pv[0]; pr[1]=pr[0];
    pv[0]=v; pr[0]=r;
}

__device__ __forceinline__ void ins3(float v, float* nv) {
    if (v >= nv[2]) return;
    if (v >= nv[1]) { nv[2]=v; return; }
    nv[2]=nv[1];
    if (v >= nv[0]) { nv[1]=v; return; }
    nv[1]=nv[0]; nv[0]=v;
}

// Pass 1: per (class, row-chunk) partial top-4 positives (val,row), top-3
// negatives (val), positive count. Coalesced: consecutive threads = consecutive c.
__global__ __launch_bounds__(256) void k1_partial(const float* __restrict__ input,
        const float* __restrict__ target, int* __restrict__ pnp,
        float* __restrict__ ppv, int* __restrict__ ppr, float* __restrict__ pnv)
{
    int c = blockIdx.x * 256 + threadIdx.x;
    int ch = blockIdx.y;
    if (c >= C_) return;
    float pv[4] = {INFINITY, INFINITY, INFINITY, INFINITY};
    int   pr[4] = {-1, -1, -1, -1};
    float nv[3] = {INFINITY, INFINITY, INFINITY};
    int npos = 0;
    int r0 = ch * RPC;
    for (int k = 0; k < RPC; ++k) {
        int i = r0 + k;
        size_t idx = (size_t)i * C_ + c;
        float x = input[idx];
        float t = target[idx];
        float pred = 1.0f / (1.0f + expf(-x));
        if (t == 1.0f) { npos++; ins4(pred, i, pv, pr); }
        else           { ins3(pred, nv); }
    }
    size_t base = (size_t)ch * C_ + c;
    pnp[base] = npos;
    #pragma unroll
    for (int j = 0; j < 4; ++j) { ppv[base*4+j] = pv[j]; ppr[base*4+j] = pr[j]; }
    #pragma unroll
    for (int l = 0; l < 3; ++l) { pnv[base*3+l] = nv[l]; }
}

// Merge 32 partials per class; emit counts, m, n_n, cleaned tops.
__global__ __launch_bounds__(256) void k1_merge(const int* __restrict__ pnp,
        const float* __restrict__ ppv, const int* __restrict__ ppr,
        const float* __restrict__ pnv,
        int* __restrict__ counts, int* __restrict__ m_arr, int* __restrict__ nn_arr,
        float* __restrict__ ptv, int* __restrict__ ptr_, float* __restrict__ ntv)
{
    int c = blockIdx.x * 256 + threadIdx.x;
    if (c >= C_) return;
    float pv[4] = {INFINITY, INFINITY, INFINITY, INFINITY};
    int   pr[4] = {-1, -1, -1, -1};
    float nv[3] = {INFINITY, INFINITY, INFINITY};
    int npos = 0;
    for (int ch = 0; ch < NCH; ++ch) {
        size_t base = (size_t)ch * C_ + c;
        npos += pnp[base];
        for (int j = 0; j < 4; ++j) {
            int rr = ppr[base*4+j];
            if (rr < 0) break;                 // sorted prefix of valid entries
            ins4(ppv[base*4+j], rr, pv, pr);
        }
        for (int l = 0; l < 3; ++l) {
            float v = pnv[base*3+l];
            if (!(v < INFINITY)) break;
            ins3(v, nv);
        }
    }
    counts[c] = npos;
    int m  = min(KK, max(npos - 1, 0));
    int nn = min(KK, B_ - npos);
    m_arr[c] = m; nn_arr[c] = nn;
    #pragma unroll
    for (int j = 0; j < 4; ++j) {
        ptv[c*4+j]  = (pv[j] < INFINITY) ? pv[j] : 0.0f;   // jnp.where(isfinite,...,0)
        ptr_[c*4+j] = pr[j];
    }
    #pragma unroll
    for (int l = 0; l < 3; ++l) ntv[c*3+l] = (nv[l] < INFINITY) ? nv[l] : 0.0f;
}

// Minority mask: stable-sort semantics without sorting.
// inclusive cumsum at class c = sum(counts < cc) + cc * #{j<=c : counts[j]==cc}.
// 8 lanes per class split the j-scan (250 each), shfl-reduce within the octet.
__global__ __launch_bounds__(256) void k2_minority(const int* __restrict__ counts,
                                                   int* __restrict__ minority)
{
    int gid  = blockIdx.x * 256 + threadIdx.x;
    int ci   = gid >> 3;
    int part = gid & 7;
    long long sless = 0; int tcnt = 0;
    int cc = 0;
    if (ci < C_) {
        cc = counts[ci];
        int j0 = part * (C_ / 8);
        for (int j = j0; j < j0 + (C_ / 8); ++j) {
            int cj = counts[j];
            if (cj < cc) sless += cj;
            if (cj == cc && j <= ci) tcnt++;
        }
    }
    sless += __shfl_down(sless, 4, 8); tcnt += __shfl_down(tcnt, 4, 8);
    sless += __shfl_down(sless, 2, 8); tcnt += __shfl_down(tcnt, 2, 8);
    sless += __shfl_down(sless, 1, 8); tcnt += __shfl_down(tcnt, 1, 8);
    if (part == 0 && ci < C_) {
        bool sel = (cc > 1) && (sless + (long long)cc * tcnt <= (long long)(B_ / 2));
        minority[ci] = sel ? 1 : 0;
    }
}

// Pass 2: bce everywhere + anchor dp/dn. float4 loads (2000 % 4 == 0, rows
// hold exactly 500 float4 so a vector never crosses a row boundary).
__global__ __launch_bounds__(256) void k3_main(const float* __restrict__ input,
        const float* __restrict__ target,
        const int* __restrict__ minority, const int* __restrict__ m_arr,
        const int* __restrict__ nn_arr, const float* __restrict__ ptv,
        const int* __restrict__ ptr_, const float* __restrict__ ntv,
        double* __restrict__ acc)
{
    double bce = 0.0, dp = 0.0, dn = 0.0;
    const size_t total4 = (size_t)B_ * C_ / 4;   // 2,048,000
    size_t stride = (size_t)gridDim.x * blockDim.x;
    for (size_t q = (size_t)blockIdx.x * blockDim.x + threadIdx.x; q < total4; q += stride) {
        float4 x4 = reinterpret_cast<const float4*>(input)[q];
        float4 t4 = reinterpret_cast<const float4*>(target)[q];
        int i  = (int)(q / (C_ / 4));
        int c0 = (int)(q % (C_ / 4)) * 4;
        #pragma unroll
        for (int k = 0; k < 4; ++k) {
            float x = (k == 0) ? x4.x : (k == 1) ? x4.y : (k == 2) ? x4.z : x4.w;
            float t = (k == 0) ? t4.x : (k == 1) ? t4.y : (k == 2) ? t4.z : t4.w;
            // softplus(x) - x*t  (matches jnp.logaddexp(0,x) = max(x,0)+log1p(exp(-|x|)))
            float sp = fmaxf(x, 0.0f) + log1pf(expf(-fabsf(x)));
            bce += (double)(sp - x * t);
            if (t == 1.0f) {
                int c = c0 + k;
                if (minority[c]) {
                    float pred = 1.0f / (1.0f + expf(-x));
                    int m  = m_arr[c];
                    int nn = nn_arr[c];
                    // rank<=K detection: is this row one of the 4 smallest positives?
                    int r = -1;
                    #pragma unroll
                    for (int j = 0; j < 4; ++j) if (ptr_[c*4+j] == i) r = j;
                    float dpos = 0.0f;
                    if (r < 0) {
                        for (int j = 0; j < m; ++j) dpos += fabsf(pred - ptv[c*4+j]);
                    } else {
                        int cnt = 0;
                        for (int j = 0; j < 4 && cnt < m; ++j) {
                            if (j == r) continue;
                            dpos += fabsf(pred - ptv[c*4+j]);
                            cnt++;
                        }
                    }
                    float dneg = 0.0f;
                    for (int l = 0; l < nn; ++l) dneg += fabsf(pred - ntv[c*3+l]);
                    dp += (double)nn * (double)dpos;
                    dn += (double)m  * (double)dneg;
                }
            }
        }
    }
    // block reduce 3 doubles: wave shuffle then LDS across 4 waves
    #pragma unroll
    for (int off = 32; off > 0; off >>= 1) {
        bce += __shfl_down(bce, off);
        dp  += __shfl_down(dp,  off);
        dn  += __shfl_down(dn,  off);
    }
    __shared__ double sb[4], sdp[4], sdn[4];
    int wave = threadIdx.x >> 6, lane = threadIdx.x & 63;
    if (lane == 0) { sb[wave] = bce; sdp[wave] = dp; sdn[wave] = dn; }
    __syncthreads();
    if (threadIdx.x == 0) {
        atomicAdd(&acc[0], sb[0] + sb[1] + sb[2] + sb[3]);
        atomicAdd(&acc[1], sdp[0] + sdp[1] + sdp[2] + sdp[3]);
        atomicAdd(&acc[2], sdn[0] + sdn[1] + sdn[2] + sdn[3]);
    }
}

__global__ void k4_final(const double* __restrict__ acc, float* __restrict__ out) {
    double bce = acc[0] / ((double)B_ * (double)C_);
    double crl = acc[1] - acc[2] + 1.0;          // MARGIN
    if (crl < 0.0) crl = 0.0;
    out[0] = (float)(0.001 * crl + 0.999 * bce); // ALPHA, 1-ALPHA
}

extern "C" void kernel_launch(void* const* d_in, const int* in_sizes, int n_in,
                              void* d_out, int out_size, void* d_ws, size_t ws_size,
                              hipStream_t stream) {
    const float* input  = (const float*)d_in[0];
    const float* target = (const float*)d_in[1];
    // d_in[2] (X) is unused by the reference output.
    float* out = (float*)d_out;
    char* ws = (char*)d_ws;

    double* acc    = (double*)(ws + OFF_ACC);
    int*    counts = (int*)   (ws + OFF_COUNTS);
    int*    m_arr  = (int*)   (ws + OFF_M);
    int*    nn_arr = (int*)   (ws + OFF_NN);
    int*    minor  = (int*)   (ws + OFF_MIN);
    float*  ptv    = (float*) (ws + OFF_PTV);
    int*    ptr_   = (int*)   (ws + OFF_PTR);
    float*  ntv    = (float*) (ws + OFF_NTV);
    int*    pnp    = (int*)   (ws + OFF_PNP);
    float*  ppv    = (float*) (ws + OFF_PPV);
    int*    ppr    = (int*)   (ws + OFF_PPR);
    float*  pnv    = (float*) (ws + OFF_PNV);

    hipMemsetAsync(acc, 0, 3 * sizeof(double), stream);

    dim3 g1((C_ + 255) / 256, NCH);
    k1_partial<<<g1, 256, 0, stream>>>(input, target, pnp, ppv, ppr, pnv);
    k1_merge<<<(C_ + 255) / 256, 256, 0, stream>>>(pnp, ppv, ppr, pnv,
                                                   counts, m_arr, nn_arr, ptv, ptr_, ntv);
    k2_minority<<<(C_ * 8 + 255) / 256, 256, 0, stream>>>(counts, minor);
    k3_main<<<2048, 256, 0, stream>>>(input, target, minor, m_arr, nn_arr,
                                      ptv, ptr_, ntv, acc);
    k4_final<<<1, 1, 0, stream>>>(acc, out);
}

// Round 2
// 171.361 us; speedup vs baseline: 2.0849x; 2.0849x over previous
//
#include <hip/hip_runtime.h>
#include <math.h>

#define C_  2000
#define B_  4096
#define KK  3
#define NCH 64            // row chunks (k1 grid.y)
#define RPC (B_ / NCH)    // 64 rows per chunk
#define SPL 4             // row splits per block (256 thr / 64 class-lanes)
#define RPS (RPC / SPL)   // 16 rows per thread
#define CPB 256           // classes per block in k1
#define NXB 8             // x-blocks (8*256 = 2048 >= 2000)

typedef unsigned long long u64;
typedef unsigned int u32;

// ---- workspace layout (bytes), total ~6.3 MB ----
constexpr size_t OFF_ACC    = 0;                                 // double[3]: bce, dp, dn
constexpr size_t OFF_COUNTS = 256;                               // int[C]
constexpr size_t OFF_M      = OFF_COUNTS + 4*(size_t)C_;         // int[C]
constexpr size_t OFF_NN     = OFF_M      + 4*(size_t)C_;         // int[C]
constexpr size_t OFF_MIN    = OFF_NN     + 4*(size_t)C_;         // int[C]
constexpr size_t OFF_PTV    = OFF_MIN    + 4*(size_t)C_;         // float[4C] pos_top cleaned
constexpr size_t OFF_PTR    = OFF_PTV    + 16*(size_t)C_;        // int[4C]   pos_top rows
constexpr size_t OFF_NTV    = OFF_PTR    + 16*(size_t)C_;        // float[3C] neg_top cleaned
constexpr size_t OFF_PPK    = (OFF_NTV + 12*(size_t)C_ + 255) & ~(size_t)255; // u64[C*NCH*4]
constexpr size_t OFF_PNV    = OFF_PPK + 8*4*(size_t)C_*NCH;      // float[C*NCH*3]
constexpr size_t OFF_PNP    = OFF_PNV + 4*3*(size_t)C_*NCH;      // int[C*NCH]

// ---- branchless sorted-insert networks ----
// keep-4-smallest u64 keys, ascending. e == ~0ull is a guaranteed no-op
// (real keys have pred bits <= 0x3F800000 in the high word).
__device__ __forceinline__ u64 umin64(u64 a, u64 b) { return a < b ? a : b; }
__device__ __forceinline__ u64 umax64(u64 a, u64 b) { return a < b ? b : a; }
__device__ __forceinline__ void pins(u64* k, u64 e) {
    k[3] = umin64(k[3], umax64(k[2], e));
    k[2] = umin64(k[2], umax64(k[1], e));
    k[1] = umin64(k[1], umax64(k[0], e));
    k[0] = umin64(k[0], e);
}
// keep-3-smallest floats, ascending. e == +INF is a no-op.
__device__ __forceinline__ void nins(float* n, float e) {
    n[2] = fminf(n[2], fmaxf(n[1], e));
    n[1] = fminf(n[1], fmaxf(n[0], e));
    n[0] = fminf(n[0], e);
}

__device__ __forceinline__ u64 shfl_xor_u64(u64 v, int mask, int width) {
    int lo = __shfl_xor((int)(u32)v, mask, width);
    int hi = __shfl_xor((int)(u32)(v >> 32), mask, width);
    return (((u64)(u32)hi) << 32) | (u32)lo;
}

// Pass 1 (the only full-data pass): per-(class, chunk) top-4 positives as
// (pred,row) keys, top-3 negatives, positive count — branchless — plus fused
// BCE partial sum. Block = 64 class-lanes (x4 classes via float4) x 4 row
// splits; splits merged through LDS so global partials stay at NCH per class.
__global__ __launch_bounds__(256) void k1_partial(
        const float* __restrict__ input, const float* __restrict__ target,
        u64* __restrict__ ppk, float* __restrict__ pnv, int* __restrict__ pnp,
        double* __restrict__ acc)
{
    __shared__ u64   lpk[SPL][CPB][4];   // 32 KB
    __shared__ float lnv[SPL][CPB][3];   // 12 KB
    __shared__ int   lnp[SPL][CPB];      //  4 KB
    __shared__ double lbce[SPL];

    const int tid = threadIdx.x;
    const int g = tid & 63;          // class-group lane
    const int s = tid >> 6;          // row split
    const int cb = blockIdx.x * CPB + g * 4;
    const bool active = (cb < C_);
    const int r0 = blockIdx.y * RPC + s * RPS;

    u64   pk[4][4];
    float nv[4][3];
    int   np[4];
    #pragma unroll
    for (int j = 0; j < 4; ++j) {
        np[j] = 0;
        #pragma unroll
        for (int q = 0; q < 4; ++q) pk[j][q] = ~0ull;
        #pragma unroll
        for (int q = 0; q < 3; ++q) nv[j][q] = INFINITY;
    }
    double bce = 0.0;

    if (active) {
        const float4* in4 = reinterpret_cast<const float4*>(input);
        const float4* tg4 = reinterpret_cast<const float4*>(target);
        const size_t base4 = ((size_t)r0 * C_ + cb) >> 2;
        #pragma unroll 4
        for (int k = 0; k < RPS; ++k) {
            size_t idx4 = base4 + (size_t)k * (C_ / 4);
            float4 x4 = in4[idx4];
            float4 t4 = tg4[idx4];
            int row = r0 + k;
            float xs[4] = {x4.x, x4.y, x4.z, x4.w};
            float ts[4] = {t4.x, t4.y, t4.z, t4.w};
            #pragma unroll
            for (int j = 0; j < 4; ++j) {
                float x = xs[j], t = ts[j];
                float e2 = expf(-fabsf(x));           // one exp per element
                float q  = 1.0f / (1.0f + e2);
                float pred = (x >= 0.0f) ? q : e2 * q; // stable sigmoid (both passes use this)
                float sp = fmaxf(x, 0.0f) + log1pf(e2); // logaddexp(0,x)
                bce += (double)(sp - x * t);
                bool pos = (t == 1.0f);
                u64 key = pos ? ((((u64)__float_as_uint(pred)) << 32) | (u32)row)
                              : ~0ull;
                pins(pk[j], key);
                nins(nv[j], pos ? INFINITY : pred);
                np[j] += pos ? 1 : 0;
            }
        }
    }

    // stash all split states in LDS
    if (active) {
        #pragma unroll
        for (int j = 0; j < 4; ++j) {
            int cl = g * 4 + j;
            #pragma unroll
            for (int q = 0; q < 4; ++q) lpk[s][cl][q] = pk[j][q];
            #pragma unroll
            for (int q = 0; q < 3; ++q) lnv[s][cl][q] = nv[j][q];
            lnp[s][cl] = np[j];
        }
    }
    // fused BCE: wave reduce, then across the 4 waves
    #pragma unroll
    for (int off = 32; off > 0; off >>= 1) bce += __shfl_down(bce, off);
    if ((tid & 63) == 0) lbce[s] = bce;
    __syncthreads();
    if (tid == 0) atomicAdd(&acc[0], lbce[0] + lbce[1] + lbce[2] + lbce[3]);

    // one thread per class merges the 4 splits and writes the chunk partial
    int c = blockIdx.x * CPB + tid;
    if (c < C_) {
        u64   mk[4] = {~0ull, ~0ull, ~0ull, ~0ull};
        float mn[3] = {INFINITY, INFINITY, INFINITY};
        int   mp = 0;
        #pragma unroll
        for (int sp = 0; sp < SPL; ++sp) {
            #pragma unroll
            for (int q = 0; q < 4; ++q) pins(mk, lpk[sp][tid][q]);
            #pragma unroll
            for (int q = 0; q < 3; ++q) nins(mn, lnv[sp][tid][q]);
            mp += lnp[sp][tid];
        }
        size_t pb = (size_t)c * NCH + blockIdx.y;
        #pragma unroll
        for (int q = 0; q < 4; ++q) ppk[pb * 4 + q] = mk[q];
        #pragma unroll
        for (int q = 0; q < 3; ++q) pnv[pb * 3 + q] = mn[q];
        pnp[pb] = mp;
    }
}

// Merge the NCH chunk partials per class: 8 lanes/class scan 8 chunks each,
// then xor-butterfly merge within the octet.
__global__ __launch_bounds__(256) void k1_merge(
        const u64* __restrict__ ppk, const float* __restrict__ pnv,
        const int* __restrict__ pnp,
        int* __restrict__ counts, int* __restrict__ m_arr, int* __restrict__ nn_arr,
        float* __restrict__ ptv, int* __restrict__ ptr_, float* __restrict__ ntv)
{
    int gid = blockIdx.x * 256 + threadIdx.x;
    int ci = gid >> 3, part = gid & 7;
    u64   pk[4] = {~0ull, ~0ull, ~0ull, ~0ull};
    float nv[3] = {INFINITY, INFINITY, INFINITY};
    int   np = 0;
    if (ci < C_) {
        #pragma unroll
        for (int t = 0; t < NCH / 8; ++t) {
            size_t pb = (size_t)ci * NCH + part + 8 * t;  // octet lanes coalesce
            np += pnp[pb];
            #pragma unroll
            for (int q = 0; q < 4; ++q) pins(pk, ppk[pb * 4 + q]);
            #pragma unroll
            for (int q = 0; q < 3; ++q) nins(nv, pnv[pb * 3 + q]);
        }
    }
    #pragma unroll
    for (int off = 4; off >= 1; off >>= 1) {
        u64 o0 = shfl_xor_u64(pk[0], off, 8);
        u64 o1 = shfl_xor_u64(pk[1], off, 8);
        u64 o2 = shfl_xor_u64(pk[2], off, 8);
        u64 o3 = shfl_xor_u64(pk[3], off, 8);
        float f0 = __shfl_xor(nv[0], off, 8);
        float f1 = __shfl_xor(nv[1], off, 8);
        float f2 = __shfl_xor(nv[2], off, 8);
        int   on = __shfl_xor(np, off, 8);
        pins(pk, o0); pins(pk, o1); pins(pk, o2); pins(pk, o3);
        nins(nv, f0); nins(nv, f1); nins(nv, f2);
        np += on;
    }
    if (part == 0 && ci < C_) {
        counts[ci] = np;
        m_arr[ci]  = min(KK, max(np - 1, 0));
        nn_arr[ci] = min(KK, B_ - np);
        #pragma unroll
        for (int q = 0; q < 4; ++q) {
            u64 k = pk[q];
            bool sent = (k == ~0ull);
            ptv[ci * 4 + q]  = sent ? 0.0f : __uint_as_float((u32)(k >> 32));
            ptr_[ci * 4 + q] = sent ? -1 : (int)(u32)(k & 0xffffffffu);
        }
        #pragma unroll
        for (int q = 0; q < 3; ++q)
            ntv[ci * 3 + q] = (nv[q] < INFINITY) ? nv[q] : 0.0f;
    }
}

// Minority mask without sorting: inclusive stable cumsum at class c
//  = sum(counts < cc) + cc * #{j<=c : counts[j]==cc}; 8 lanes split the scan.
__global__ __launch_bounds__(256) void k2_minority(const int* __restrict__ counts,
                                                   int* __restrict__ minority)
{
    int gid  = blockIdx.x * 256 + threadIdx.x;
    int ci   = gid >> 3;
    int part = gid & 7;
    long long sless = 0; int tcnt = 0;
    int cc = 0;
    if (ci < C_) {
        cc = counts[ci];
        int j0 = part * (C_ / 8);
        for (int j = j0; j < j0 + (C_ / 8); ++j) {
            int cj = counts[j];
            if (cj < cc) sless += cj;
            if (cj == cc && j <= ci) tcnt++;
        }
    }
    sless += __shfl_down(sless, 4, 8); tcnt += __shfl_down(tcnt, 4, 8);
    sless += __shfl_down(sless, 2, 8); tcnt += __shfl_down(tcnt, 2, 8);
    sless += __shfl_down(sless, 1, 8); tcnt += __shfl_down(tcnt, 1, 8);
    if (part == 0 && ci < C_) {
        bool sel = (cc > 1) && (sless + (long long)cc * tcnt <= (long long)(B_ / 2));
        minority[ci] = sel ? 1 : 0;
    }
}

// Anchor pass: one block per class; non-minority blocks (all but ~80) exit
// immediately. Column reads are L3-warm from pass 1.
__global__ __launch_bounds__(256) void k3_anchor(
        const float* __restrict__ input, const float* __restrict__ target,
        const int* __restrict__ minority, const int* __restrict__ m_arr,
        const int* __restrict__ nn_arr, const float* __restrict__ ptv,
        const int* __restrict__ ptr_, const float* __restrict__ ntv,
        double* __restrict__ acc)
{
    int c = blockIdx.x;
    if (minority[c] == 0) return;
    int m  = m_arr[c];
    int nn = nn_arr[c];
    float pv0 = ptv[c*4+0], pv1 = ptv[c*4+1], pv2 = ptv[c*4+2], pv3 = ptv[c*4+3];
    int   pr0 = ptr_[c*4+0], pr1 = ptr_[c*4+1], pr2 = ptr_[c*4+2], pr3 = ptr_[c*4+3];
    float nv0 = ntv[c*3+0], nv1 = ntv[c*3+1], nv2 = ntv[c*3+2];
    double dp = 0.0, dn = 0.0;
    #pragma unroll 4
    for (int i = threadIdx.x; i < B_; i += 256) {
        float x = input[(size_t)i * C_ + c];
        float t = target[(size_t)i * C_ + c];
        if (t == 1.0f) {
            float e2 = expf(-fabsf(x));
            float q  = 1.0f / (1.0f + e2);
            float pred = (x >= 0.0f) ? q : e2 * q;   // same expr as k1 -> exact row match
            int r = -1;
            if (pr0 == i) r = 0;
            if (pr1 == i) r = 1;
            if (pr2 == i) r = 2;
            if (pr3 == i) r = 3;
            float pvv[4] = {pv0, pv1, pv2, pv3};
            float dpos = 0.0f;
            if (r < 0) {
                for (int j = 0; j < m; ++j) dpos += fabsf(pred - pvv[j]);
            } else {
                int cnt = 0;
                for (int j = 0; j < 4 && cnt < m; ++j) {
                    if (j == r) continue;
                    dpos += fabsf(pred - pvv[j]);
                    cnt++;
                }
            }
            float nvv[3] = {nv0, nv1, nv2};
            float dneg = 0.0f;
            for (int l = 0; l < nn; ++l) dneg += fabsf(pred - nvv[l]);
            dp += (double)nn * (double)dpos;
            dn += (double)m  * (double)dneg;
        }
    }
    #pragma unroll
    for (int off = 32; off > 0; off >>= 1) {
        dp += __shfl_down(dp, off);
        dn += __shfl_down(dn, off);
    }
    __shared__ double sdp[4], sdn[4];
    int wave = threadIdx.x >> 6, lane = threadIdx.x & 63;
    if (lane == 0) { sdp[wave] = dp; sdn[wave] = dn; }
    __syncthreads();
    if (threadIdx.x == 0) {
        atomicAdd(&acc[1], sdp[0] + sdp[1] + sdp[2] + sdp[3]);
        atomicAdd(&acc[2], sdn[0] + sdn[1] + sdn[2] + sdn[3]);
    }
}

__global__ void k4_final(const double* __restrict__ acc, float* __restrict__ out) {
    double bce = acc[0] / ((double)B_ * (double)C_);
    double crl = acc[1] - acc[2] + 1.0;            // MARGIN
    if (crl < 0.0) crl = 0.0;
    out[0] = (float)(0.001 * crl + 0.999 * bce);   // ALPHA, 1-ALPHA
}

extern "C" void kernel_launch(void* const* d_in, const int* in_sizes, int n_in,
                              void* d_out, int out_size, void* d_ws, size_t ws_size,
                              hipStream_t stream) {
    const float* input  = (const float*)d_in[0];
    const float* target = (const float*)d_in[1];
    // d_in[2] (X) does not affect the reference output.
    float* out = (float*)d_out;
    char* ws = (char*)d_ws;

    double* acc    = (double*)(ws + OFF_ACC);
    int*    counts = (int*)   (ws + OFF_COUNTS);
    int*    m_arr  = (int*)   (ws + OFF_M);
    int*    nn_arr = (int*)   (ws + OFF_NN);
    int*    minor  = (int*)   (ws + OFF_MIN);
    float*  ptv    = (float*) (ws + OFF_PTV);
    int*    ptr_   = (int*)   (ws + OFF_PTR);
    float*  ntv    = (float*) (ws + OFF_NTV);
    u64*    ppk    = (u64*)   (ws + OFF_PPK);
    float*  pnv    = (float*) (ws + OFF_PNV);
    int*    pnp    = (int*)   (ws + OFF_PNP);

    hipMemsetAsync(acc, 0, 3 * sizeof(double), stream);

    k1_partial<<<dim3(NXB, NCH), 256, 0, stream>>>(input, target, ppk, pnv, pnp, acc);
    k1_merge<<<(C_ * 8 + 255) / 256, 256, 0, stream>>>(ppk, pnv, pnp,
                                                       counts, m_arr, nn_arr, ptv, ptr_, ntv);
    k2_minority<<<(C_ * 8 + 255) / 256, 256, 0, stream>>>(counts, minor);
    k3_anchor<<<C_, 256, 0, stream>>>(input, target, minor, m_arr, nn_arr,
                                      ptv, ptr_, ntv, acc);
    k4_final<<<1, 1, 0, stream>>>(acc, out);
}

// Round 3
// 147.639 us; speedup vs baseline: 2.4199x; 1.1607x over previous
//
#include <hip/hip_runtime.h>
#include <math.h>

#define C_  2000
#define B_  4096
#define KK  3
#define NXB 8             // class-blocks: 8*256 = 2048 >= 2000
#define NCH 128           // row chunks
#define RPC (B_ / NCH)    // 32 rows per chunk
#define SPL 4             // waves per block = row splits
#define RPS (RPC / SPL)   // 8 rows per thread
#define K3B 1024          // k3 grid = ticket total (>= worst-case nmin)

typedef unsigned long long u64;
typedef unsigned int u32;

// ---- workspace layout (bytes) ----
constexpr size_t OFF_ACC    = 0;                      // double[3]: bce, dp, dn
constexpr size_t OFF_DONE   = 24;                     // int ticket
constexpr size_t OFF_NMIN   = 28;                     // int
constexpr size_t OFF_COUNTS = 32;                     // int[C_]
constexpr size_t ZERO_BYTES = OFF_COUNTS + 4*(size_t)C_;   // 8032 — one memset
constexpr size_t OFF_MLIST  = (ZERO_BYTES + 63) & ~(size_t)63; // int[K3B]

// branchless keep-4-smallest u64 keys (ascending); ~0ull is a no-op insert
__device__ __forceinline__ u64 umin64(u64 a, u64 b) { return a < b ? a : b; }
__device__ __forceinline__ u64 umax64(u64 a, u64 b) { return a < b ? b : a; }
__device__ __forceinline__ void pins(u64* k, u64 e) {
    k[3] = umin64(k[3], umax64(k[2], e));
    k[2] = umin64(k[2], umax64(k[1], e));
    k[1] = umin64(k[1], umax64(k[0], e));
    k[0] = umin64(k[0], e);
}
// branchless keep-3-smallest floats; +INF is a no-op
__device__ __forceinline__ void nins(float* n, float e) {
    n[2] = fminf(n[2], fmaxf(n[1], e));
    n[1] = fminf(n[1], fmaxf(n[0], e));
    n[0] = fminf(n[0], e);
}

// Pass 1 — the ONLY full-data pass: BCE + per-class positive counts.
// No top-k state at all (recomputed later for ~80 minority classes only).
__global__ __launch_bounds__(256) void k1_bce_counts(
        const float* __restrict__ input, const float* __restrict__ target,
        int* __restrict__ counts, double* __restrict__ acc)
{
    __shared__ int lnp[256];
    __shared__ double lb[SPL];
    const int tid = threadIdx.x;
    lnp[tid] = 0;
    __syncthreads();

    const int g  = tid & 63;          // class lane
    const int s  = tid >> 6;          // row split (= wave)
    const int cb = blockIdx.x * 256 + g * 4;
    const int r0 = blockIdx.y * RPC + s * RPS;
    const bool active = (cb < C_);

    double bce = 0.0;
    int np0 = 0, np1 = 0, np2 = 0, np3 = 0;
    if (active) {
        const float4* in4 = reinterpret_cast<const float4*>(input);
        const float4* tg4 = reinterpret_cast<const float4*>(target);
        const size_t base4 = ((size_t)r0 * C_ + cb) >> 2;
        #pragma unroll
        for (int k = 0; k < RPS; ++k) {
            size_t idx4 = base4 + (size_t)k * (C_ / 4);
            float4 x4 = in4[idx4];
            float4 t4 = tg4[idx4];
            // softplus(x) - x*t with fast exp/log (final threshold is 1.6e-2)
            float e0 = __expf(-fabsf(x4.x)), e1 = __expf(-fabsf(x4.y));
            float e2 = __expf(-fabsf(x4.z)), e3 = __expf(-fabsf(x4.w));
            float b0 = fmaxf(x4.x, 0.0f) + __logf(1.0f + e0) - x4.x * t4.x;
            float b1 = fmaxf(x4.y, 0.0f) + __logf(1.0f + e1) - x4.y * t4.y;
            float b2 = fmaxf(x4.z, 0.0f) + __logf(1.0f + e2) - x4.z * t4.z;
            float b3 = fmaxf(x4.w, 0.0f) + __logf(1.0f + e3) - x4.w * t4.w;
            bce += (double)((b0 + b1) + (b2 + b3));
            np0 += (t4.x == 1.0f); np1 += (t4.y == 1.0f);
            np2 += (t4.z == 1.0f); np3 += (t4.w == 1.0f);
        }
        atomicAdd(&lnp[g * 4 + 0], np0);
        atomicAdd(&lnp[g * 4 + 1], np1);
        atomicAdd(&lnp[g * 4 + 2], np2);
        atomicAdd(&lnp[g * 4 + 3], np3);
    }
    // BCE: wave shuffle reduce, then across waves via LDS, one atomic/block
    #pragma unroll
    for (int off = 32; off > 0; off >>= 1) bce += __shfl_down(bce, off);
    if (g == 0) lb[s] = bce;
    __syncthreads();
    if (tid == 0) atomicAdd(&acc[0], lb[0] + lb[1] + lb[2] + lb[3]);
    int cidx = blockIdx.x * 256 + tid;
    if (cidx < C_ && lnp[tid] != 0) atomicAdd(&counts[cidx], lnp[tid]);
}

// Minority selection (stable-sort semantics without sorting):
// inclusive cumsum at class c = sum(counts<cc) + cc * #{j<=c: counts[j]==cc}.
// One wave per class; counts staged in LDS. Emits compacted list + count.
__global__ __launch_bounds__(256) void k2_minority(
        const int* __restrict__ counts, int* __restrict__ mlist, int* __restrict__ nmin)
{
    __shared__ int lc[C_];
    for (int j = threadIdx.x; j < C_; j += 256) lc[j] = counts[j];
    __syncthreads();
    int w = threadIdx.x >> 6, lane = threadIdx.x & 63;
    int ci = blockIdx.x * 4 + w;              // grid 500 * 4 = 2000 exact
    int cc = lc[ci];
    int sless = 0, tcnt = 0;
    #pragma unroll 4
    for (int j = lane; j < C_; j += 64) {
        int cj = lc[j];
        sless += (cj < cc) ? cj : 0;
        tcnt  += (cj == cc && j <= ci) ? 1 : 0;
    }
    #pragma unroll
    for (int off = 32; off > 0; off >>= 1) {
        sless += __shfl_down(sless, off);
        tcnt  += __shfl_down(tcnt, off);
    }
    if (lane == 0) {
        if (cc > 1 && (sless + cc * tcnt) <= (B_ / 2)) {
            int idx = atomicAdd(nmin, 1);
            mlist[idx] = ci;
        }
    }
}

// Anchor pass + finalize: one block per minority slot. Active blocks scan
// their class column (L3-warm), stash signed preds in LDS, block-merge exact
// (pred,row) u64 top-4 positives + f32 top-3 negatives, then compute dp/dn.
// Last block (device ticket) folds the final scalar — no separate kernel.
__global__ __launch_bounds__(256) void k3_anchor_final(
        const float* __restrict__ input, const float* __restrict__ target,
        const int* __restrict__ counts, const int* __restrict__ mlist,
        const int* __restrict__ nmin, double* __restrict__ acc,
        int* __restrict__ done, float* __restrict__ out)
{
    __shared__ float sval[B_];        // 16 KB: +pred if positive, -pred if negative
    __shared__ u64   lpk[4][4];
    __shared__ float lnv[4][3];
    __shared__ double lred[4][2];
    const int tid = threadIdx.x;
    const int w = tid >> 6, lane = tid & 63;
    const int nm = *nmin;

    if (blockIdx.x < nm) {
        const int c = mlist[blockIdx.x];
        u64   pk[4] = {~0ull, ~0ull, ~0ull, ~0ull};
        float nv[3] = {INFINITY, INFINITY, INFINITY};
        #pragma unroll 4
        for (int i = tid; i < B_; i += 256) {
            float x = input[(size_t)i * C_ + c];
            float t = target[(size_t)i * C_ + c];
            float e2 = __expf(-fabsf(x));
            float q  = __builtin_amdgcn_rcpf(1.0f + e2);
            float pred = (x >= 0.0f) ? q : e2 * q;   // pred in (0,1), never 0
            bool pos = (t == 1.0f);
            sval[i] = pos ? pred : -pred;
            pins(pk, pos ? ((((u64)__float_as_uint(pred)) << 32) | (u32)i) : ~0ull);
            nins(nv, pos ? INFINITY : pred);
        }
        // wave reduce (lane 0 accumulates), then cross-wave via LDS
        #pragma unroll
        for (int off = 32; off > 0; off >>= 1) {
            u64 o0 = __shfl_down(pk[0], off), o1 = __shfl_down(pk[1], off);
            u64 o2 = __shfl_down(pk[2], off), o3 = __shfl_down(pk[3], off);
            float f0 = __shfl_down(nv[0], off), f1 = __shfl_down(nv[1], off);
            float f2 = __shfl_down(nv[2], off);
            pins(pk, o0); pins(pk, o1); pins(pk, o2); pins(pk, o3);
            nins(nv, f0); nins(nv, f1); nins(nv, f2);
        }
        if (lane == 0) {
            #pragma unroll
            for (int q2 = 0; q2 < 4; ++q2) lpk[w][q2] = pk[q2];
            #pragma unroll
            for (int q2 = 0; q2 < 3; ++q2) lnv[w][q2] = nv[q2];
        }
        __syncthreads();
        u64   fk[4] = {~0ull, ~0ull, ~0ull, ~0ull};
        float fn[3] = {INFINITY, INFINITY, INFINITY};
        #pragma unroll
        for (int w2 = 0; w2 < 4; ++w2) {
            #pragma unroll
            for (int q2 = 0; q2 < 4; ++q2) pins(fk, lpk[w2][q2]);
            #pragma unroll
            for (int q2 = 0; q2 < 3; ++q2) nins(fn, lnv[w2][q2]);
        }
        const int np = counts[c];
        const int m  = min(KK, max(np - 1, 0));
        const int nn = min(KK, B_ - np);
        float pv[4];
        #pragma unroll
        for (int q2 = 0; q2 < 4; ++q2) pv[q2] = __uint_as_float((u32)(fk[q2] >> 32));
        // entries beyond the real count are sentinels but proven never read:
        // dpos touches first m (<= np-1) others; dneg first nn (<= 4096-np).
        double dp = 0.0, dn = 0.0;
        for (int i = tid; i < B_; i += 256) {
            float sv = sval[i];
            if (sv > 0.0f) {                        // anchor (positive, minority class)
                float pred = sv;
                u64 key = (((u64)__float_as_uint(pred)) << 32) | (u32)i;
                int r = -1;
                #pragma unroll
                for (int q2 = 0; q2 < 4; ++q2) if (fk[q2] == key) r = q2;
                float dpos = 0.0f;
                if (r < 0) {
                    for (int j = 0; j < m; ++j) dpos += fabsf(pred - pv[j]);
                } else {
                    int cnt = 0;
                    #pragma unroll
                    for (int j = 0; j < 4; ++j) {
                        if (j != r && cnt < m) { dpos += fabsf(pred - pv[j]); cnt++; }
                    }
                }
                float dneg = 0.0f;
                for (int l = 0; l < nn; ++l) dneg += fabsf(pred - fn[l]);
                dp += (double)nn * (double)dpos;
                dn += (double)m  * (double)dneg;
            }
        }
        #pragma unroll
        for (int off = 32; off > 0; off >>= 1) {
            dp += __shfl_down(dp, off);
            dn += __shfl_down(dn, off);
        }
        if (lane == 0) { lred[w][0] = dp; lred[w][1] = dn; }
        __syncthreads();
        if (tid == 0) {
            atomicAdd(&acc[1], lred[0][0] + lred[1][0] + lred[2][0] + lred[3][0]);
            atomicAdd(&acc[2], lred[0][1] + lred[1][1] + lred[2][1] + lred[3][1]);
        }
    }
    // ticket: every block (active or not) participates; last one finalizes
    if (tid == 0) {
        __threadfence();
        int old = atomicAdd(done, 1);
        if (old == K3B - 1) {
            double b   = atomicAdd(&acc[0], 0.0);   // coherent reads
            double dpv = atomicAdd(&acc[1], 0.0);
            double dnv = atomicAdd(&acc[2], 0.0);
            double bce = b / ((double)B_ * (double)C_);
            double crl = dpv - dnv + 1.0;           // MARGIN
            if (crl < 0.0) crl = 0.0;
            out[0] = (float)(0.001 * crl + 0.999 * bce);  // ALPHA, 1-ALPHA
        }
    }
}

extern "C" void kernel_launch(void* const* d_in, const int* in_sizes, int n_in,
                              void* d_out, int out_size, void* d_ws, size_t ws_size,
                              hipStream_t stream) {
    const float* input  = (const float*)d_in[0];
    const float* target = (const float*)d_in[1];
    // d_in[2] (X) does not affect the reference output.
    float* out = (float*)d_out;
    char* ws = (char*)d_ws;

    double* acc    = (double*)(ws + OFF_ACC);
    int*    done   = (int*)   (ws + OFF_DONE);
    int*    nmin   = (int*)   (ws + OFF_NMIN);
    int*    counts = (int*)   (ws + OFF_COUNTS);
    int*    mlist  = (int*)   (ws + OFF_MLIST);

    hipMemsetAsync(ws, 0, ZERO_BYTES, stream);   // acc + done + nmin + counts

    k1_bce_counts<<<dim3(NXB, NCH), 256, 0, stream>>>(input, target, counts, acc);
    k2_minority<<<C_ / 4, 256, 0, stream>>>(counts, mlist, nmin);
    k3_anchor_final<<<K3B, 256, 0, stream>>>(input, target, counts, mlist, nmin,
                                             acc, done, out);
}